// Round 1
// baseline (1471.202 us; speedup 1.0000x reference)
//
#include <hip/hip_runtime.h>

// NATTEN 3D neighborhood attention, exact-window fp32 baseline.
// Shapes fixed by setup_inputs(): B=1, T=16, H=32, W=32, nh=8, D=128,
// window (3,7,7), non-causal, stride 1. Output fp32 [1, L, nh, D].
//
// Per-query key window (matches reference mask exactly):
//   st_t = clip(t-1, 0, T-3); st_h = clip(h-3, 0, H-7); st_w = clip(w-3, 0, W-7)
//   keys = [st_t, st_t+3) x [st_h, st_h+7) x [st_w, st_w+7)   (147 keys)
//
// Block = one head x (1,4,8) query tile -> 32 queries, 256 threads.
// Halo (3,10,14) staged into LDS in 6 chunks of (1,5,14)=70 rows.
// thread = (qi in [0,32), g in [0,8));  g owns dims [16g, 16g+16).
// Phase 1: QK -> scores LDS; softmax; Phase 2: restage V, PV.

namespace {

constexpr int T = 16, H = 32, W = 32, NH = 8, D = 128;
constexpr int QH = 4, QW = 8;           // query tile (1 x QH x QW)
constexpr int NQ = QH * QW;             // 32 queries / block
constexpr int HALO_H = QH + 6;          // 10
constexpr int HALO_W = QW + 6;          // 14
constexpr int CH = 5;                   // halo h-rows per staged chunk (2 chunks)
constexpr int ROWS = CH * HALO_W;       // 70 rows per chunk
constexpr int RSTRIDE = D + 4;          // 132 floats, pad to break bank stride
constexpr int NKEY = 3 * 7 * 7;         // 147
constexpr int SSTRIDE = 148;            // score row stride (147 -> 148)
constexpr float SCALE = 0.088388347648318447f;  // 128^-0.5

__global__ __launch_bounds__(256) void na3d(const float* __restrict__ qp,
                                            const float* __restrict__ kp,
                                            const float* __restrict__ vp,
                                            float* __restrict__ op) {
  __shared__ float buf[ROWS * RSTRIDE];   // 36,960 B staged K or V chunk
  __shared__ float sc[NQ * SSTRIDE];      // 18,944 B scores -> probs
  __shared__ float linv[NQ];              // 1/rowsum

  int bid = blockIdx.x;
  const int wb = bid & 3;  bid >>= 2;   // W/QW = 4
  const int hb = bid & 7;  bid >>= 3;   // H/QH = 8
  const int t  = bid & 15; bid >>= 4;   // T = 16
  const int head = bid;                 // NH = 8

  const int h0 = hb * QH, w0 = wb * QW;
  const int bT = min(max(t - 1, 0), T - 3);
  const int bH = min(max(h0 - 3, 0), H - HALO_H);
  const int bW = min(max(w0 - 3, 0), W - HALO_W);

  const int tid = threadIdx.x;
  const int qi = tid >> 3;              // 0..31  (wave-uniform hl: qi>>3)
  const int g  = tid & 7;               // 16-dim chunk
  const int hl = qi >> 3, wl = qi & 7;
  const int gh = h0 + hl, gw = w0 + wl;
  const int aH = min(max(gh - 3, 0), H - 7) - bH;   // 0..3, wave-uniform
  const int aW = min(max(gw - 3, 0), W - 7) - bW;   // 0..7

  // q fragment (16 dims), pre-scaled
  const size_t qoff = ((size_t)((t * H + gh) * W + gw) * NH + head) * D + g * 16;
  float4 qv[4];
  {
    const float4* p4 = (const float4*)(qp + qoff);
#pragma unroll
    for (int u = 0; u < 4; ++u) {
      qv[u] = p4[u];
      qv[u].x *= SCALE; qv[u].y *= SCALE; qv[u].z *= SCALE; qv[u].w *= SCALE;
    }
  }

  // ---- stage one (1, CH, HALO_W) chunk of K or V into LDS ----
  auto stage = [&](const float* __restrict__ src, int dt, int ch) {
    const int tt = bT + dt;
    const int hbase = bH + ch * CH;
    for (int idx = tid; idx < ROWS * (D / 4); idx += 256) {
      const int r = idx >> 5;           // row 0..69
      const int c = idx & 31;           // float4 index within row
      const int hh = hbase + r / HALO_W;
      const int ww = bW + r % HALO_W;
      const size_t off = ((size_t)((tt * H + hh) * W + ww) * NH + head) * D + c * 4;
      const float4 val = *(const float4*)(src + off);
      *(float4*)(&buf[r * RSTRIDE + c * 4]) = val;
    }
  };

  // per-(dt,chunk) window row range for this thread's query (wave-uniform)
  auto irange = [&](int ch, int& i0, int& i1) {
    i0 = (ch == 0) ? 0 : (CH - aH);
    i1 = (ch == 0) ? (CH - aH) : 7;
  };

  // ================= Phase 1: QK^T =================
  for (int dt = 0; dt < 3; ++dt) {
    for (int ch = 0; ch < 2; ++ch) {
      __syncthreads();                  // prior chunk's reads complete
      stage(kp, dt, ch);
      __syncthreads();
      int i0, i1; irange(ch, i0, i1);
      for (int i = i0; i < i1; ++i) {
        const int rbase = (aH + i - ch * CH) * HALO_W + aW;
#pragma unroll
        for (int j = 0; j < 7; ++j) {
          const float* bp = &buf[(rbase + j) * RSTRIDE + g * 16];
          float acc = 0.f;
#pragma unroll
          for (int u = 0; u < 4; ++u) {
            const int uu = (u + g) & 3;   // rotate to spread LDS banks
            const float4 b = *(const float4*)(bp + uu * 4);
            const float4 a = qv[uu];
            acc += a.x * b.x + a.y * b.y + a.z * b.z + a.w * b.w;
          }
          // reduce the 8 g-partials (lanes qi*8+g within the wave)
          acc += __shfl_xor(acc, 1);
          acc += __shfl_xor(acc, 2);
          acc += __shfl_xor(acc, 4);
          if (g == 0) sc[qi * SSTRIDE + dt * 49 + i * 7 + j] = acc;
        }
      }
    }
  }
  __syncthreads();

  // ================= softmax (one thread per query) =================
  if (tid < NQ) {
    float* row = &sc[tid * SSTRIDE];
    float m = -1e30f;
    for (int j = 0; j < NKEY; ++j) m = fmaxf(m, row[j]);
    float s = 0.f;
    for (int j = 0; j < NKEY; ++j) {
      const float e = __expf(row[j] - m);
      row[j] = e;
      s += e;
    }
    linv[tid] = 1.f / s;
  }

  // ================= Phase 2: P @ V =================
  float4 ov[4] = {};
  for (int dt = 0; dt < 3; ++dt) {
    for (int ch = 0; ch < 2; ++ch) {
      __syncthreads();                  // scores ready / prior reads done
      stage(vp, dt, ch);
      __syncthreads();
      int i0, i1; irange(ch, i0, i1);
      for (int i = i0; i < i1; ++i) {
        const int rbase = (aH + i - ch * CH) * HALO_W + aW;
        const float* srow = &sc[qi * SSTRIDE + dt * 49 + i * 7];
#pragma unroll
        for (int j = 0; j < 7; ++j) {
          const float p = srow[j];
          const float* bp = &buf[(rbase + j) * RSTRIDE + g * 16];
#pragma unroll
          for (int u = 0; u < 4; ++u) {
            const int uu = (u + g) & 3;
            const float4 b = *(const float4*)(bp + uu * 4);
            ov[uu].x += p * b.x; ov[uu].y += p * b.y;
            ov[uu].z += p * b.z; ov[uu].w += p * b.w;
          }
        }
      }
    }
  }

  const float li = linv[qi];
#pragma unroll
  for (int u = 0; u < 4; ++u) {
    float4 r = ov[u];
    r.x *= li; r.y *= li; r.z *= li; r.w *= li;
    *(float4*)(op + qoff + u * 4) = r;
  }
}

}  // namespace

extern "C" void kernel_launch(void* const* d_in, const int* in_sizes, int n_in,
                              void* d_out, int out_size, void* d_ws, size_t ws_size,
                              hipStream_t stream) {
  const float* q = (const float*)d_in[0];
  const float* k = (const float*)d_in[1];
  const float* v = (const float*)d_in[2];
  float* out = (float*)d_out;
  // grid: head-major, then t, hb, wb (wb fastest -> spatial L2 locality)
  const int nblocks = NH * T * (H / QH) * (W / QW);  // 4096
  na3d<<<dim3(nblocks), dim3(256), 0, stream>>>(q, k, v, out);
}

// Round 3
// 586.044 us; speedup vs baseline: 2.5104x; 2.5104x over previous
//
#include <hip/hip_runtime.h>

// NATTEN 3D neighborhood attention — fp16 MFMA flash-style.
// B=1, T=16, H=32, W=32, nh=8, D=128, window (3,7,7), fp32 in/out.
//
// Block = one head x (1,4,8) query tile (32 queries), 256 threads (4 waves).
// Dense halo keys 3x10x14=420, processed as 6 chunks of (1,5,14)=70 keys
// (padded to 80 for QK n-tiles, 96 for PV k-steps; invalid keys masked to
// P=0 before PV, and V frags for keys 70..95 ZEROED — 0*uninit = NaN bug
// fixed in R3). Online softmax (m,l per query) across chunks.
// GEMM1: S^T[80][32] = (Q[32x128] * K^T)   via mfma_f32_16x16x32_f16
// GEMM2: O[32][128] += P[32x96] * V[96x128] via mfma_f32_16x16x32_f16
// All MFMA operands stored in LDS in frag-order (lane-linear 16B slots):
// conflict-free ds_read_b128. LDS total ~51.8 KB -> 3 blocks/CU.

typedef _Float16 f16;
typedef _Float16 half8 __attribute__((ext_vector_type(8)));
typedef float floatx4 __attribute__((ext_vector_type(4)));

namespace {

constexpr int T = 16, H = 32, W = 32, NH = 8, D = 128;
constexpr int QH = 4, QW = 8;
constexpr float SCALE = 0.088388347648318447f;  // 128^-0.5

__device__ __forceinline__ size_t goff(int tt, int hh, int ww, int head) {
  return ((size_t)((tt * H + hh) * W + ww) * NH + head) * D;
}

__global__ __launch_bounds__(256) void na3d_mfma(
    const float* __restrict__ qp, const float* __restrict__ kp,
    const float* __restrict__ vp, float* __restrict__ op) {
  // frag-order buffers: slot = ((tile*ksteps + ks)*64 + lane) * 8 f16
  __shared__ alignas(16) f16 qbuf[2 * 4 * 64 * 8];    // Q  A-frags  8192 B
  __shared__ alignas(16) f16 kvbuf[8 * 3 * 64 * 8];   // K/V B-frags 24576 B
  __shared__ alignas(16) float st[80 * 33];           // S^T [key][q] 10560 B
  __shared__ alignas(16) f16 pbuf[2 * 3 * 64 * 8];    // P  A-frags  6144 B
  __shared__ alignas(16) float red[8 * 32];           // max/sum partials
  __shared__ alignas(16) float mnew[32];              // row max (then 1/l)
  __shared__ alignas(16) float alphas[32];            // rescale factors

  int bid = blockIdx.x;
  const int wb = bid & 3;  bid >>= 2;
  const int hb = bid & 7;  bid >>= 3;
  const int t  = bid & 15; bid >>= 4;
  const int head = bid;

  const int h0 = hb * QH, w0 = wb * QW;
  const int bT = min(max(t - 1, 0), T - 3);
  const int bH = min(max(h0 - 3, 0), H - 10);
  const int bW = min(max(w0 - 3, 0), W - 14);

  const int tid = threadIdx.x;
  const int wave = tid >> 6, lane = tid & 63;
  const int quad = lane >> 4, ln = lane & 15;

  // ---- Q staging: frag-order, pre-scaled, fp32->fp16 ----
  for (int s = tid; s < 512; s += 256) {
    const int q = s >> 4, dg = s & 15;
    const size_t off = goff(t, h0 + (q >> 3), w0 + (q & 7), head) + dg * 8;
    const float4 x0 = *(const float4*)(qp + off);
    const float4 x1 = *(const float4*)(qp + off + 4);
    half8 hv;
    hv[0] = (f16)(x0.x * SCALE); hv[1] = (f16)(x0.y * SCALE);
    hv[2] = (f16)(x0.z * SCALE); hv[3] = (f16)(x0.w * SCALE);
    hv[4] = (f16)(x1.x * SCALE); hv[5] = (f16)(x1.y * SCALE);
    hv[6] = (f16)(x1.z * SCALE); hv[7] = (f16)(x1.w * SCALE);
    const int mt = q >> 4, m = q & 15, ks = dg >> 2, qd = dg & 3;
    *(half8*)&qbuf[(((mt * 4 + ks) * 64) + qd * 16 + m) * 8] = hv;
  }

  floatx4 oacc[4] = {{0.f, 0.f, 0.f, 0.f}, {0.f, 0.f, 0.f, 0.f},
                     {0.f, 0.f, 0.f, 0.f}, {0.f, 0.f, 0.f, 0.f}};
  const int mt2 = wave & 1, nd0 = (wave >> 1) * 4;  // GEMM2 tile ownership

  float m_run = -1e30f, l_run = 0.f;  // live in tid<32 only

  // softmax thread mapping: sq = query, sp = key-partition
  const int sq = tid & 31, sp = tid >> 5;
  const int aH = min(max(h0 + (sq >> 3) - 3, 0), H - 7) - bH;  // 0..3
  const int aW = min(max(w0 + (sq & 7) - 3, 0), W - 7) - bW;   // 0..7

  for (int c = 0; c < 6; ++c) {
    const int dt = c >> 1, hh = c & 1;
    const int tt = bT + dt;
    const int kh0 = bH + hh * 5;

    __syncthreads();  // protect kvbuf from prior GEMM2 reads
    // ---- K staging: frag-order (rows are contiguous dims -> 16B copies) --
    for (int s = tid; s < 1120; s += 256) {
      const int kk = s >> 4, dg = s & 15;
      const int khl = kk / 14, kw = kk - khl * 14;
      const size_t off = goff(tt, kh0 + khl, bW + kw, head) + dg * 8;
      const float4 x0 = *(const float4*)(kp + off);
      const float4 x1 = *(const float4*)(kp + off + 4);
      half8 hv;
      hv[0] = (f16)x0.x; hv[1] = (f16)x0.y; hv[2] = (f16)x0.z; hv[3] = (f16)x0.w;
      hv[4] = (f16)x1.x; hv[5] = (f16)x1.y; hv[6] = (f16)x1.z; hv[7] = (f16)x1.w;
      const int nt = kk >> 4, n = kk & 15, ks = dg >> 2, qd = dg & 3;
      *(half8*)&kvbuf[(((nt * 4 + ks) * 64) + qd * 16 + n) * 8] = hv;
    }
    __syncthreads();

    // ---- GEMM1: S^T = Q * K^T  (10 tiles = 2 mt x 5 nt over 4 waves) ----
    for (int tile = wave; tile < 10; tile += 4) {
      const int mt = tile / 5, nt = tile - mt * 5;
      floatx4 acc = {0.f, 0.f, 0.f, 0.f};
#pragma unroll
      for (int ks = 0; ks < 4; ++ks) {
        const half8 a = *(const half8*)&qbuf[(((mt * 4 + ks) * 64) + lane) * 8];
        const half8 b = *(const half8*)&kvbuf[(((nt * 4 + ks) * 64) + lane) * 8];
        acc = __builtin_amdgcn_mfma_f32_16x16x32_f16(a, b, acc, 0, 0, 0);
      }
      // D layout: col(lane&15)=key-within-tile, row(quad*4+reg)=query
      float* dst = &st[(nt * 16 + ln) * 33 + mt * 16 + quad * 4];
      dst[0] = acc[0]; dst[1] = acc[1]; dst[2] = acc[2]; dst[3] = acc[3];
    }
    __syncthreads();

    // ---- softmax pass 1: chunk row max (valid window only) ----
    float pm = -1e30f;
#pragma unroll
    for (int i = 0; i < 12; ++i) {
      const int kk = sp * 12 + i;
      if (kk < 70) {
        const int khl = kk / 14, kw = kk - khl * 14;
        const int kha = hh * 5 + khl;
        if (kha >= aH && kha < aH + 7 && kw >= aW && kw < aW + 7)
          pm = fmaxf(pm, st[kk * 33 + sq]);
      }
    }
    red[sp * 32 + sq] = pm;
    __syncthreads();
    if (tid < 32) {
      float mc = red[tid];
#pragma unroll
      for (int p = 1; p < 8; ++p) mc = fmaxf(mc, red[p * 32 + tid]);
      const float mN = fmaxf(m_run, mc);
      const float a = __expf(m_run - mN);
      m_run = mN; l_run *= a;
      mnew[tid] = mN; alphas[tid] = a;
    }
    __syncthreads();

    // ---- pass 2: P = exp(S-m), frag-order f16; partial row sums ----
    const float mq = mnew[sq];
    float ps = 0.f;
#pragma unroll
    for (int i = 0; i < 12; ++i) {
      const int kk = sp * 12 + i;  // 0..95 covers all of pbuf
      f16 pv = (f16)0.f;
      if (kk < 70) {
        const int khl = kk / 14, kw = kk - khl * 14;
        const int kha = hh * 5 + khl;
        if (kha >= aH && kha < aH + 7 && kw >= aW && kw < aW + 7) {
          const float e = __expf(st[kk * 33 + sq] - mq);
          ps += e; pv = (f16)e;
        }
      }
      pbuf[((((sq >> 4) * 3 + (kk >> 5)) * 64) + ((kk >> 3) & 3) * 16 +
            (sq & 15)) * 8 + (kk & 7)] = pv;
    }
    red[sp * 32 + sq] = ps;

    // ---- V staging: transpose into B-frag order (b16 scatters) ----
    // keys 0..69 from global; keys 70..95 ZEROED (P=0 there, but MFMA would
    // still propagate NaN from uninitialized LDS: 0*NaN = NaN).
    for (int s = tid; s < 1536; s += 256) {
      const int kk = s >> 4, dg = s & 15;
      float xs[8] = {0.f, 0.f, 0.f, 0.f, 0.f, 0.f, 0.f, 0.f};
      if (kk < 70) {
        const int khl = kk / 14, kw = kk - khl * 14;
        const size_t off = goff(tt, kh0 + khl, bW + kw, head) + dg * 8;
        const float4 x0 = *(const float4*)(vp + off);
        const float4 x1 = *(const float4*)(vp + off + 4);
        xs[0] = x0.x; xs[1] = x0.y; xs[2] = x0.z; xs[3] = x0.w;
        xs[4] = x1.x; xs[5] = x1.y; xs[6] = x1.z; xs[7] = x1.w;
      }
      const int kst = kk >> 5, qd = (kk >> 3) & 3, j = kk & 7;
      const int d0 = dg * 8;
#pragma unroll
      for (int u = 0; u < 8; ++u) {
        const int d = d0 + u;
        kvbuf[((((d >> 4) * 3 + kst) * 64) + qd * 16 + (d & 15)) * 8 + j] =
            (f16)xs[u];
      }
    }
    __syncthreads();

    if (tid < 32) {
      float s2 = 0.f;
#pragma unroll
      for (int p = 0; p < 8; ++p) s2 += red[p * 32 + tid];
      l_run += s2;  // l = alpha*l_old + rowsum (alpha applied above)
    }

    // ---- GEMM2: O = alpha*O + P*V ----
    const floatx4 af = *(const floatx4*)&alphas[mt2 * 16 + quad * 4];
#pragma unroll
    for (int u = 0; u < 4; ++u) oacc[u] *= af;
#pragma unroll
    for (int ks = 0; ks < 3; ++ks) {
      const half8 a = *(const half8*)&pbuf[(((mt2 * 3 + ks) * 64) + lane) * 8];
#pragma unroll
      for (int u = 0; u < 4; ++u) {
        const half8 b =
            *(const half8*)&kvbuf[((((nd0 + u) * 3 + ks) * 64) + lane) * 8];
        oacc[u] = __builtin_amdgcn_mfma_f32_16x16x32_f16(a, b, oacc[u], 0, 0, 0);
      }
    }
  }

  // ---- epilogue: O / l, write out ----
  __syncthreads();
  if (tid < 32) mnew[tid] = 1.f / l_run;  // reuse mnew as linv
  __syncthreads();
  const floatx4 lf = *(const floatx4*)&mnew[mt2 * 16 + quad * 4];
#pragma unroll
  for (int r = 0; r < 4; ++r) {
    const int q = mt2 * 16 + quad * 4 + r;
    const size_t off = goff(t, h0 + (q >> 3), w0 + (q & 7), head);
#pragma unroll
    for (int u = 0; u < 4; ++u)
      op[off + (nd0 + u) * 16 + ln] = oacc[u][r] * lf[r];
  }
}

}  // namespace

extern "C" void kernel_launch(void* const* d_in, const int* in_sizes, int n_in,
                              void* d_out, int out_size, void* d_ws,
                              size_t ws_size, hipStream_t stream) {
  const float* q = (const float*)d_in[0];
  const float* k = (const float*)d_in[1];
  const float* v = (const float*)d_in[2];
  float* out = (float*)d_out;
  const int nblocks = NH * T * (H / QH) * (W / QW);  // 4096
  na3d_mfma<<<dim3(nblocks), dim3(256), 0, stream>>>(q, k, v, out);
}